// Round 10
// baseline (334.660 us; speedup 1.0000x reference)
//
#include <hip/hip_runtime.h>

// Problem constants
#define NB 16
#define NS 512
#define ND 2048
#define NH 16
#define NG 4
#define NHD 128
#define NM (NB * NS)      // 8192 rows (b*s)
#define NKD (NG * NHD)    // 512
#define NKV 1024          // fused K|V row width
#define HEAD_SCALE 0.08838834764831845f

typedef _Float16 h8 __attribute__((ext_vector_type(8)));
typedef float fx4 __attribute__((ext_vector_type(4)));

// global -> LDS direct copy, 16B per lane. LDS dest is wave-uniform base + lane*16.
__device__ __forceinline__ void gload16(const void* g, void* l) {
  __builtin_amdgcn_global_load_lds(
      (__attribute__((address_space(1))) void*)(unsigned long long)g,
      (__attribute__((address_space(3))) void*)(unsigned long long)l,
      16, 0, 0);
}

// ---------------- fused prep kernel ----------------
// block ranges: [0,2048) cvt_x | [2048,3072) wtrans wq | [3072,3328) wtrans wk |
// [3328,3584) wtrans wv | [3584,4608) wtrans wo | [4608,4736) rope | [4736] bias.

__global__ void prep_kernel(const float* __restrict__ x, _Float16* __restrict__ xh,
                            const float* __restrict__ wq, _Float16* __restrict__ wqt,
                            const float* __restrict__ wk, const float* __restrict__ wv,
                            _Float16* __restrict__ wkvt,
                            const float* __restrict__ wo, _Float16* __restrict__ wot,
                            float* __restrict__ cosT, float* __restrict__ sinT,
                            const float* __restrict__ bk, const float* __restrict__ bv,
                            float* __restrict__ bkv) {
  __shared__ float t[64][65];
  const int bid = blockIdx.x, tid = threadIdx.x;
  if (bid < 2048) {
    const fx4* p = (const fx4*)x;
    h8* o = (h8*)xh;
#pragma unroll
    for (int it = 0; it < 4; ++it) {
      int i = (it * 2048 + bid) * 256 + tid;
      fx4 a = p[2 * i], b = p[2 * i + 1];
      h8 hv;
      hv[0] = (_Float16)a[0]; hv[1] = (_Float16)a[1]; hv[2] = (_Float16)a[2]; hv[3] = (_Float16)a[3];
      hv[4] = (_Float16)b[0]; hv[5] = (_Float16)b[1]; hv[6] = (_Float16)b[2]; hv[7] = (_Float16)b[3];
      o[i] = hv;
    }
    return;
  }
  int lb = bid - 2048;
  const float* src;
  _Float16* dst;
  int K, N;
  if (lb < 1024)      { src = wq; dst = wqt; K = ND; N = ND; }
  else if (lb < 1280) { lb -= 1024; src = wk; dst = wkvt; K = ND; N = NKD; }
  else if (lb < 1536) { lb -= 1280; src = wv; dst = wkvt + (size_t)NKD * ND; K = ND; N = NKD; }
  else if (lb < 2560) { lb -= 1536; src = wo; dst = wot; K = ND; N = ND; }
  else if (lb < 2688) {
    int i = (lb - 2560) * 256 + tid;
    int s = i >> 6, f = i & 63;
    float inv = exp2f(-(float)f * (13.287712379549449f / 64.0f));
    float a = (float)s * inv;
    cosT[i] = cosf(a);
    sinT[i] = sinf(a);
    return;
  } else {
#pragma unroll
    for (int it = 0; it < 4; ++it) {
      int idx = it * 256 + tid;
      bkv[idx] = (idx < NKD) ? bk[idx] : bv[idx - NKD];
    }
    return;
  }
  const int ntil = N >> 6;
  const int n0 = (lb % ntil) * 64, k0 = (lb / ntil) * 64;
#pragma unroll
  for (int it = 0; it < 16; ++it) {
    int idx = it * 256 + tid;
    int r = idx >> 6, c = idx & 63;
    t[r][c] = src[(size_t)(k0 + r) * N + n0 + c];
  }
  __syncthreads();
#pragma unroll
  for (int it = 0; it < 16; ++it) {
    int idx = it * 256 + tid;
    int r = idx >> 6, c = idx & 63;
    dst[(size_t)(n0 + r) * K + k0 + c] = (_Float16)t[c][r];
  }
}

// V part of fused KV buffer -> Vt[b*4+g][128 d][512 s]
__global__ void vtrans_kernel(const _Float16* __restrict__ kv, _Float16* __restrict__ vt) {
  __shared__ _Float16 t[64][72];
  int st = blockIdx.x, dt = blockIdx.y, bg = blockIdx.z;
  int b = bg >> 2, g = bg & 3;
  const _Float16* src = kv + ((size_t)(b * NS + st * 64)) * NKV + NKD + g * NHD + dt * 64;
#pragma unroll
  for (int it = 0; it < 2; ++it) {
    int idx = it * 256 + threadIdx.x;
    int r = idx >> 3, c = (idx & 7) * 8;
    *(h8*)&t[r][c] = *(const h8*)(src + (size_t)r * NKV + c);
  }
  __syncthreads();
  _Float16* dst = vt + ((size_t)bg * NHD + dt * 64) * NS + st * 64;
#pragma unroll
  for (int it = 0; it < 2; ++it) {
    int idx = it * 256 + threadIdx.x;
    int r = idx >> 3, c = (idx & 7) * 8;
    h8 o;
#pragma unroll
    for (int e = 0; e < 8; ++e) o[e] = t[c + e][r];
    *(h8*)(dst + (size_t)r * NS + c) = o;
  }
}

// merged Q-norm + K-norm: [0,32768) Q rows/heads, [32768,40960) K rows/heads
__global__ void norm_rope_kernel(_Float16* __restrict__ Qb, _Float16* __restrict__ KVb,
                                 const float* __restrict__ qns, const float* __restrict__ kns,
                                 const float* __restrict__ cosT, const float* __restrict__ sinT) {
  int bid = blockIdx.x;
  _Float16* X;
  const float* scale;
  int hshift, rowStride;
  float outScale;
  if (bid < 32768) { X = Qb; scale = qns; hshift = 4; rowStride = ND; outScale = HEAD_SCALE; }
  else { bid -= 32768; X = KVb; scale = kns; hshift = 2; rowStride = NKV; outScale = 1.0f; }
  int wid = threadIdx.x >> 6, lane = threadIdx.x & 63;
  int task = bid * 4 + wid;
  int row = task >> hshift;
  int head = task & ((1 << hshift) - 1);
  _Float16* p = X + (size_t)row * rowStride + head * NHD;
  float x1 = (float)p[lane], x2 = (float)p[lane + 64];
  float ss = x1 * x1 + x2 * x2;
#pragma unroll
  for (int m = 1; m < 64; m <<= 1) ss += __shfl_xor(ss, m, 64);
  float rn = rsqrtf(ss * (1.0f / 128.0f) + 1e-6f);
  int s = row & (NS - 1);
  float c = cosT[s * 64 + lane], sn = sinT[s * 64 + lane];
  float n1 = x1 * rn * scale[lane], n2 = x2 * rn * scale[64 + lane];
  p[lane] = (_Float16)((n1 * c - n2 * sn) * outScale);
  p[lane + 64] = (_Float16)((n1 * sn + n2 * c) * outScale);
}

__device__ __forceinline__ void st_out(float* p, float v) { *p = v; }
__device__ __forceinline__ void st_out(_Float16* p, float v) { *p = (_Float16)v; }

// ---------------- GEMM 128x128 (2-phase) — used for the KV projection ----------------

template <typename OT>
__global__ __launch_bounds__(256, 3) void gemm_bt_kernel(
    const _Float16* __restrict__ A, const _Float16* __restrict__ Bt,
    const float* __restrict__ bias, OT* __restrict__ C, int N, int K) {
  __shared__ alignas(16) _Float16 As[128 * 64];
  __shared__ alignas(16) _Float16 Bs[128 * 64];
  const int tid = threadIdx.x;
  const int lane = tid & 63, wid = tid >> 6;
  const int wr = wid >> 1, wc = wid & 1;
  const int la = lane & 15, lb = (lane >> 4) * 8;
  const int bm = blockIdx.y * 128, bn = blockIdx.x * 128;

  fx4 acc[4][4] = {};

  for (int kt = 0; kt < K; kt += 64) {
    const _Float16* Ag = A + (size_t)bm * K + kt;
    const _Float16* Bg = Bt + (size_t)bn * K + kt;
#pragma unroll
    for (int it = 0; it < 4; ++it) {
      int cb = it * 256 + wid * 64;
      int ca = cb + lane;
      int r = ca >> 3, cc = ca & 7;
      gload16(Ag + (size_t)r * K + cc * 8, &As[cb * 8]);
      gload16(Bg + (size_t)r * K + cc * 8, &Bs[cb * 8]);
    }
    __syncthreads();
#pragma unroll
    for (int kk = 0; kk < 2; ++kk) {
      h8 af[4], bf[4];
#pragma unroll
      for (int m = 0; m < 4; ++m)
        af[m] = *(const h8*)&As[(wr * 64 + m * 16 + la) * 64 + kk * 32 + lb];
#pragma unroll
      for (int n = 0; n < 4; ++n)
        bf[n] = *(const h8*)&Bs[(wc * 64 + n * 16 + la) * 64 + kk * 32 + lb];
#pragma unroll
      for (int m = 0; m < 4; ++m)
#pragma unroll
        for (int n = 0; n < 4; ++n)
          acc[m][n] = __builtin_amdgcn_mfma_f32_16x16x32_f16(af[m], bf[n], acc[m][n], 0, 0, 0);
    }
    __syncthreads();
  }
#pragma unroll
  for (int m = 0; m < 4; ++m) {
    int row0 = bm + wr * 64 + m * 16 + (lane >> 4) * 4;
#pragma unroll
    for (int n = 0; n < 4; ++n) {
      int col = bn + wc * 64 + n * 16 + la;
      float bvv = bias[col];
#pragma unroll
      for (int r = 0; r < 4; ++r)
        st_out(&C[(size_t)(row0 + r) * N + col], acc[m][n][r] + bvv);
    }
  }
}

// ---------------- GEMM 256x256, fine-interleaved 4-phase (r8-verified) ------------
// 512 threads = 8 waves (2M x 4N). K-tile (BK=64) split into 2 k-halves of 32.
// LDS: As/Bs[2 buf][2 khalf][256*32] = 128 KB. Per phase: {ds_reads (4A, +4B at
// g=0) -> 2 stage gloads of tile kt+1 -> [ph1/ph3: vmcnt(4)] -> s_barrier ->
// lgkmcnt(0) -> setprio(1)+16 MFMA+setprio(0) -> s_barrier}. Seal chain in r8
// notes. Swizzle: chunk c ^= (r>>1)&3 (bank-verified free); inverse on stage
// source, forward on ds_read (rule 21). Measured: 75.5us, 0 conflicts.

template <typename OT>
__global__ __launch_bounds__(512, 2) void gemm256_kernel(
    const _Float16* __restrict__ A, const _Float16* __restrict__ Bt,
    const float* __restrict__ bias, OT* __restrict__ C, int N, int K) {
  __shared__ alignas(16) _Float16 As[2][2][256 * 32];
  __shared__ alignas(16) _Float16 Bs[2][2][256 * 32];
  const int tid = threadIdx.x;
  const int lane = tid & 63, w = tid >> 6;
  const int wr = w >> 2, wc = w & 3;
  const int la = lane & 15, lq = lane >> 4;
  const int lin = (blockIdx.x & 7) * 32 + (blockIdx.x >> 3);
  const int nbx = N >> 8;
  const int by = lin / nbx, bx = lin % nbx;
  const int bm = by * 256, bn = bx * 256;
  const int NT = K >> 6;

  fx4 acc[8][4] = {};

  {
    const _Float16* Ag = A + (size_t)bm * K;
    const _Float16* Bg = Bt + (size_t)bn * K;
#pragma unroll
    for (int sh = 0; sh < 2; ++sh) {
#pragma unroll
      for (int i = 0; i < 2; ++i) {
        int cb = i * 512 + w * 64;
        int s = cb + lane;
        int r = s >> 2, c = s & 3;
        gload16(Ag + (size_t)r * K + sh * 32 + ((c ^ ((r >> 1) & 3)) << 3), &As[0][sh][cb * 8]);
      }
#pragma unroll
      for (int i = 0; i < 2; ++i) {
        int cb = i * 512 + w * 64;
        int s = cb + lane;
        int r = s >> 2, c = s & 3;
        gload16(Bg + (size_t)r * K + sh * 32 + ((c ^ ((r >> 1) & 3)) << 3), &Bs[0][sh][cb * 8]);
      }
    }
  }
  asm volatile("s_waitcnt vmcnt(4)" ::: "memory");
  __builtin_amdgcn_s_barrier();

  for (int kt = 0; kt < NT; ++kt) {
    const int cur = kt & 1;
    const int nxt = cur ^ 1;
    const bool more = (kt + 1 < NT);
    const _Float16* Ag = A + (size_t)bm * K + (kt + 1) * 64;
    const _Float16* Bg = Bt + (size_t)bn * K + (kt + 1) * 64;
    h8 bf[4];
#pragma unroll
    for (int ph = 0; ph < 4; ++ph) {
      const int kh = ph >> 1, g = ph & 1;
      h8 af[4];
#pragma unroll
      for (int mi = 0; mi < 4; ++mi) {
        int row = wr * 128 + (g * 4 + mi) * 16 + la;
        af[mi] = *(const h8*)&As[cur][kh][row * 32 + ((lq ^ ((row >> 1) & 3)) << 3)];
      }
      if (g == 0) {
#pragma unroll
        for (int ni = 0; ni < 4; ++ni) {
          int row = wc * 64 + ni * 16 + la;
          bf[ni] = *(const h8*)&Bs[cur][kh][row * 32 + ((lq ^ ((row >> 1) & 3)) << 3)];
        }
      }
      if (more) {
        const int sh = ph >> 1;
        const _Float16* Sg = (ph & 1) ? Bg : Ag;
        _Float16* Ld = (ph & 1) ? &Bs[nxt][sh][0] : &As[nxt][sh][0];
#pragma unroll
        for (int i = 0; i < 2; ++i) {
          int cb = i * 512 + w * 64;
          int s = cb + lane;
          int r = s >> 2, c = s & 3;
          gload16(Sg + (size_t)r * K + sh * 32 + ((c ^ ((r >> 1) & 3)) << 3), Ld + cb * 8);
        }
      }
      if (ph == 1 || ph == 3) {
        if (more) asm volatile("s_waitcnt vmcnt(4)" ::: "memory");
        else      asm volatile("s_waitcnt vmcnt(0)" ::: "memory");
      }
      __builtin_amdgcn_s_barrier();
      asm volatile("s_waitcnt lgkmcnt(0)" ::: "memory");
      __builtin_amdgcn_sched_barrier(0);
      __builtin_amdgcn_s_setprio(1);
#pragma unroll
      for (int mi = 0; mi < 4; ++mi)
#pragma unroll
        for (int ni = 0; ni < 4; ++ni)
          acc[g * 4 + mi][ni] = __builtin_amdgcn_mfma_f32_16x16x32_f16(
              af[mi], bf[ni], acc[g * 4 + mi][ni], 0, 0, 0);
      __builtin_amdgcn_s_setprio(0);
      __builtin_amdgcn_sched_barrier(0);
      __builtin_amdgcn_s_barrier();
    }
  }
#pragma unroll
  for (int mi = 0; mi < 8; ++mi) {
    int row0 = bm + wr * 128 + mi * 16 + lq * 4;
#pragma unroll
    for (int ni = 0; ni < 4; ++ni) {
      int col = bn + wc * 64 + ni * 16 + la;
      float bvv = bias[col];
#pragma unroll
      for (int r = 0; r < 4; ++r)
        st_out(&C[(size_t)(row0 + r) * N + col], acc[mi][ni][r] + bvv);
    }
  }
}

// ---------------- flash attention ----------------
// 512 blocks x 512 threads; block = (q-tile pair, g, b); 9 kt-tiles/block.
// T4 applied: per tile {issue stage(t+1) -> vmcnt(4) counted (tile t's loads
// sealed; t+1's 4 stay in flight) -> s_barrier -> compute}. No full drains.
// Q fragments hoisted to kernel entry (qfA/qfB, uniform select) so mid-loop
// vmcnt counting sees only stage loads (+ output stores on 2/9 tiles).

__global__ __launch_bounds__(512, 4) void attn_kernel(
    const _Float16* __restrict__ Q, const _Float16* __restrict__ KV,
    const _Float16* __restrict__ Vt, _Float16* __restrict__ ctx) {
  __shared__ alignas(16) _Float16 Ks[2][64 * 128];
  __shared__ alignas(16) _Float16 Vs[2][128 * 64];
  __shared__ alignas(16) _Float16 Ps[8][16 * 64];

  const int bid = blockIdx.x;
  const int logical = (bid & 7) * 64 + (bid >> 3);
  const int b = logical >> 5;
  const int g = (logical >> 3) & 3;
  const int jp = logical & 7;
  const int j1 = jp, j2 = 15 - jp;

  const int tid = threadIdx.x;
  const int lane = tid & 63, w = tid >> 6;
  const int la = lane & 15, lq = lane >> 4;
  const int h = g * 4 + (w & 3);
  const int rh = w >> 2;

  const _Float16* Vg = Vt + (size_t)(b * NG + g) * NHD * NS;

  auto stage = [&](int buf, int kt) {
    const _Float16* Kg = KV + ((size_t)(b * NS + kt * 64)) * NKV + g * NHD;
#pragma unroll
    for (int it = 0; it < 2; ++it) {
      int cb = it * 512 + w * 64;
      int s = cb + lane;
      int rr = s >> 4, c = s & 15;
      gload16(Kg + (size_t)rr * NKV + ((c ^ (rr & 7)) * 8), &Ks[buf][cb * 8]);
    }
#pragma unroll
    for (int it = 0; it < 2; ++it) {
      int cb = it * 512 + w * 64;
      int s = cb + lane;
      int rr = s >> 3, c = s & 7;
      gload16(Vg + (size_t)rr * NS + kt * 64 + ((c ^ (rr & 7)) * 8), &Vs[buf][cb * 8]);
    }
  };

  const int nt1 = ((j1 * 32 + 31) >> 6) + 1;
  const int nt2 = ((j2 * 32 + 31) >> 6) + 1;
  const int ntotal = nt1 + nt2;  // == 9

  stage(0, 0);
  // hoisted Q fragments for both q-tiles
  h8 qfA[4], qfB[4];
  {
    const _Float16* QgA = Q + ((size_t)(b * NS + j1 * 32 + rh * 16 + la)) * ND + h * NHD + lq * 8;
    const _Float16* QgB = Q + ((size_t)(b * NS + j2 * 32 + rh * 16 + la)) * ND + h * NHD + lq * 8;
#pragma unroll
    for (int kc = 0; kc < 4; ++kc) {
      qfA[kc] = *(const h8*)(QgA + kc * 32);
      qfB[kc] = *(const h8*)(QgB + kc * 32);
    }
  }

  fx4 oacc[8];
  float mrun[4], lrun[4];

  int cur = 0;
  for (int t = 0; t < ntotal; ++t) {
    const bool inA = t < nt1;
    const int j = inA ? j1 : j2;
    const int kt = inA ? t : t - nt1;
    const int ntj = inA ? nt1 : nt2;
    const bool more = (t + 1 < ntotal);
    if (more) {
      int nkt = (t + 1 < nt1) ? (t + 1) : (t + 1 - nt1);
      stage(cur ^ 1, nkt);
      asm volatile("s_waitcnt vmcnt(4)" ::: "memory");  // tile t sealed; t+1 in flight
    } else {
      asm volatile("s_waitcnt vmcnt(0)" ::: "memory");
    }
    __builtin_amdgcn_s_barrier();
    if (kt == 0) {
#pragma unroll
      for (int f = 0; f < 8; ++f) oacc[f] = fx4{0.f, 0.f, 0.f, 0.f};
#pragma unroll
      for (int r = 0; r < 4; ++r) { mrun[r] = -1e30f; lrun[r] = 0.f; }
    }

    // QK^T: 16 q-rows x 64 kv
    fx4 sc[4] = {};
    __builtin_amdgcn_s_setprio(1);
#pragma unroll
    for (int n = 0; n < 4; ++n) {
      int row = n * 16 + la;
#pragma unroll
      for (int kc = 0; kc < 4; ++kc) {
        h8 qv = inA ? qfA[kc] : qfB[kc];
        h8 bk = *(const h8*)&Ks[cur][row * 128 + (((kc * 4 + lq) ^ (la & 7)) * 8)];
        sc[n] = __builtin_amdgcn_mfma_f32_16x16x32_f16(qv, bk, sc[n], 0, 0, 0);
      }
    }
    __builtin_amdgcn_s_setprio(0);

    const int qrow0 = j * 32 + rh * 16 + lq * 4;
    const bool maskT = (kt == ntj - 1);
    float pv[4][4];
    float rm[4] = {-1e30f, -1e30f, -1e30f, -1e30f};
#pragma unroll
    for (int n = 0; n < 4; ++n) {
      int kv = kt * 64 + n * 16 + la;
#pragma unroll
      for (int r = 0; r < 4; ++r) {
        float sv = sc[n][r] * HEAD_SCALE;
        sv = (maskT && kv > qrow0 + r) ? -1e30f : sv;
        pv[n][r] = sv;
        rm[r] = fmaxf(rm[r], sv);
      }
    }
#pragma unroll
    for (int r = 0; r < 4; ++r) {
#pragma unroll
      for (int m = 1; m < 16; m <<= 1) rm[r] = fmaxf(rm[r], __shfl_xor(rm[r], m, 64));
      float mn = fmaxf(mrun[r], rm[r]);
      float corr = __expf(mrun[r] - mn);
      mrun[r] = mn;
      lrun[r] *= corr;
#pragma unroll
      for (int f = 0; f < 8; ++f) oacc[f][r] *= corr;
    }
    float rs[4] = {0.f, 0.f, 0.f, 0.f};
#pragma unroll
    for (int n = 0; n < 4; ++n)
#pragma unroll
      for (int r = 0; r < 4; ++r) {
        float e = __expf(pv[n][r] - mrun[r]);
        pv[n][r] = e;
        rs[r] += e;
      }
#pragma unroll
    for (int r = 0; r < 4; ++r) {
#pragma unroll
      for (int m = 1; m < 16; m <<= 1) rs[r] += __shfl_xor(rs[r], m, 64);
      lrun[r] += rs[r];
    }

    // P (C-layout) -> LDS (swizzled) -> reload in A-layout (wave-local)
#pragma unroll
    for (int n = 0; n < 4; ++n)
#pragma unroll
      for (int r = 0; r < 4; ++r) {
        int row = lq * 4 + r;
        int chsw = (n * 2 + (la >> 3)) ^ (row & 7);
        Ps[w][row * 64 + chsw * 8 + (la & 7)] = (_Float16)pv[n][r];
      }
    asm volatile("s_waitcnt lgkmcnt(0)" ::: "memory");
    __builtin_amdgcn_sched_barrier(0);
    h8 pf[2];
#pragma unroll
    for (int ks = 0; ks < 2; ++ks)
      pf[ks] = *(const h8*)&Ps[w][la * 64 + (((ks * 4 + lq) ^ (la & 7)) * 8)];

    // PV
    __builtin_amdgcn_s_setprio(1);
#pragma unroll
    for (int f = 0; f < 8; ++f) {
      int row = f * 16 + la;
#pragma unroll
      for (int ks = 0; ks < 2; ++ks) {
        h8 bv = *(const h8*)&Vs[cur][row * 64 + (((ks * 4 + lq) ^ (la & 7)) * 8)];
        oacc[f] = __builtin_amdgcn_mfma_f32_16x16x32_f16(pf[ks], bv, oacc[f], 0, 0, 0);
      }
    }
    __builtin_amdgcn_s_setprio(0);

    if (maskT) {
      _Float16* Cg = ctx + ((size_t)(b * NS + qrow0)) * ND + h * NHD + la;
      float inv_l[4];
#pragma unroll
      for (int r = 0; r < 4; ++r) inv_l[r] = 1.0f / lrun[r];
#pragma unroll
      for (int f = 0; f < 8; ++f)
#pragma unroll
        for (int r = 0; r < 4; ++r)
          Cg[(size_t)r * ND + f * 16] = (_Float16)(oacc[f][r] * inv_l[r]);
    }
    cur ^= 1;
  }
}

// ---------------- launch ----------------

extern "C" void kernel_launch(void* const* d_in, const int* in_sizes, int n_in,
                              void* d_out, int out_size, void* d_ws, size_t ws_size,
                              hipStream_t stream) {
  (void)in_sizes; (void)n_in; (void)out_size; (void)ws_size;
  const float* x = (const float*)d_in[0];
  const float* wq = (const float*)d_in[1];
  const float* bq = (const float*)d_in[2];
  const float* wk = (const float*)d_in[3];
  const float* bk = (const float*)d_in[4];
  const float* wv = (const float*)d_in[5];
  const float* bv = (const float*)d_in[6];
  const float* wo = (const float*)d_in[7];
  const float* bo = (const float*)d_in[8];
  const float* qns = (const float*)d_in[9];
  const float* kns = (const float*)d_in[10];

  char* ws = (char*)d_ws;
  size_t off = 0;
  _Float16* xh = (_Float16*)(ws + off); off += (size_t)NM * ND * 2;       // 32MB
  _Float16* wqt = (_Float16*)(ws + off); off += (size_t)ND * ND * 2;      // 8MB
  _Float16* wkvt = (_Float16*)(ws + off); off += (size_t)NKV * ND * 2;    // 4MB
  _Float16* wot = (_Float16*)(ws + off); off += (size_t)ND * ND * 2;      // 8MB
  _Float16* Qb = (_Float16*)(ws + off); off += (size_t)NM * ND * 2;       // 32MB
  _Float16* KVbuf = (_Float16*)(ws + off); off += (size_t)NM * NKV * 2;   // 16MB
  float* cosT = (float*)(ws + off); off += (size_t)NS * 64 * 4;
  float* sinT = (float*)(ws + off); off += (size_t)NS * 64 * 4;
  float* bkv = (float*)(ws + off); off += (size_t)NKV * 4;
  _Float16* ctx = xh;            // xh dead after KV GEMM; reuse
  _Float16* Vtg = wqt;           // wqt dead after Q GEMM; reuse

  prep_kernel<<<dim3(4737), 256, 0, stream>>>(x, xh, wq, wqt, wk, wv, wkvt, wo, wot,
                                              cosT, sinT, bk, bv, bkv);

  gemm256_kernel<_Float16><<<dim3(256), dim3(512), 0, stream>>>(xh, wqt, bq, Qb, ND, ND);
  gemm_bt_kernel<_Float16><<<dim3(NKV / 128, NM / 128), 256, 0, stream>>>(xh, wkvt, bkv, KVbuf, NKV, ND);

  norm_rope_kernel<<<dim3(40960), 256, 0, stream>>>(Qb, KVbuf, qns, kns, cosT, sinT);

  vtrans_kernel<<<dim3(NS / 64, NHD / 64, NB * NG), 256, 0, stream>>>(KVbuf, Vtg);

  attn_kernel<<<dim3(512), dim3(512), 0, stream>>>(Qb, KVbuf, Vtg, ctx);

  gemm256_kernel<float><<<dim3(256), dim3(512), 0, stream>>>(ctx, wot, bo, (float*)d_out, ND, ND);
}

// Round 11
// 297.706 us; speedup vs baseline: 1.1241x; 1.1241x over previous
//
#include <hip/hip_runtime.h>

// Problem constants
#define NB 16
#define NS 512
#define ND 2048
#define NH 16
#define NG 4
#define NHD 128
#define NM (NB * NS)      // 8192 rows (b*s)
#define NKD (NG * NHD)    // 512
#define NKV 1024          // fused K|V row width
#define HEAD_SCALE 0.08838834764831845f

typedef _Float16 h8 __attribute__((ext_vector_type(8)));
typedef float fx4 __attribute__((ext_vector_type(4)));

// global -> LDS direct copy, 16B per lane. LDS dest is wave-uniform base + lane*16.
__device__ __forceinline__ void gload16(const void* g, void* l) {
  __builtin_amdgcn_global_load_lds(
      (__attribute__((address_space(1))) void*)(unsigned long long)g,
      (__attribute__((address_space(3))) void*)(unsigned long long)l,
      16, 0, 0);
}

// ---------------- fused prep kernel ----------------
// block ranges: [0,2048) cvt_x | [2048,3072) wtrans wq | [3072,3328) wtrans wk |
// [3328,3584) wtrans wv | [3584,4608) wtrans wo | [4608,4736) rope | [4736] bias.

__global__ void prep_kernel(const float* __restrict__ x, _Float16* __restrict__ xh,
                            const float* __restrict__ wq, _Float16* __restrict__ wqt,
                            const float* __restrict__ wk, const float* __restrict__ wv,
                            _Float16* __restrict__ wkvt,
                            const float* __restrict__ wo, _Float16* __restrict__ wot,
                            float* __restrict__ cosT, float* __restrict__ sinT,
                            const float* __restrict__ bk, const float* __restrict__ bv,
                            float* __restrict__ bkv) {
  __shared__ float t[64][65];
  const int bid = blockIdx.x, tid = threadIdx.x;
  if (bid < 2048) {
    const fx4* p = (const fx4*)x;
    h8* o = (h8*)xh;
#pragma unroll
    for (int it = 0; it < 4; ++it) {
      int i = (it * 2048 + bid) * 256 + tid;
      fx4 a = p[2 * i], b = p[2 * i + 1];
      h8 hv;
      hv[0] = (_Float16)a[0]; hv[1] = (_Float16)a[1]; hv[2] = (_Float16)a[2]; hv[3] = (_Float16)a[3];
      hv[4] = (_Float16)b[0]; hv[5] = (_Float16)b[1]; hv[6] = (_Float16)b[2]; hv[7] = (_Float16)b[3];
      o[i] = hv;
    }
    return;
  }
  int lb = bid - 2048;
  const float* src;
  _Float16* dst;
  int K, N;
  if (lb < 1024)      { src = wq; dst = wqt; K = ND; N = ND; }
  else if (lb < 1280) { lb -= 1024; src = wk; dst = wkvt; K = ND; N = NKD; }
  else if (lb < 1536) { lb -= 1280; src = wv; dst = wkvt + (size_t)NKD * ND; K = ND; N = NKD; }
  else if (lb < 2560) { lb -= 1536; src = wo; dst = wot; K = ND; N = ND; }
  else if (lb < 2688) {
    int i = (lb - 2560) * 256 + tid;
    int s = i >> 6, f = i & 63;
    float inv = exp2f(-(float)f * (13.287712379549449f / 64.0f));
    float a = (float)s * inv;
    cosT[i] = cosf(a);
    sinT[i] = sinf(a);
    return;
  } else {
#pragma unroll
    for (int it = 0; it < 4; ++it) {
      int idx = it * 256 + tid;
      bkv[idx] = (idx < NKD) ? bk[idx] : bv[idx - NKD];
    }
    return;
  }
  const int ntil = N >> 6;
  const int n0 = (lb % ntil) * 64, k0 = (lb / ntil) * 64;
#pragma unroll
  for (int it = 0; it < 16; ++it) {
    int idx = it * 256 + tid;
    int r = idx >> 6, c = idx & 63;
    t[r][c] = src[(size_t)(k0 + r) * N + n0 + c];
  }
  __syncthreads();
#pragma unroll
  for (int it = 0; it < 16; ++it) {
    int idx = it * 256 + tid;
    int r = idx >> 6, c = idx & 63;
    dst[(size_t)(n0 + r) * K + k0 + c] = (_Float16)t[c][r];
  }
}

// V part of fused KV buffer -> Vt[b*4+g][128 d][512 s]
__global__ void vtrans_kernel(const _Float16* __restrict__ kv, _Float16* __restrict__ vt) {
  __shared__ _Float16 t[64][72];
  int st = blockIdx.x, dt = blockIdx.y, bg = blockIdx.z;
  int b = bg >> 2, g = bg & 3;
  const _Float16* src = kv + ((size_t)(b * NS + st * 64)) * NKV + NKD + g * NHD + dt * 64;
#pragma unroll
  for (int it = 0; it < 2; ++it) {
    int idx = it * 256 + threadIdx.x;
    int r = idx >> 3, c = (idx & 7) * 8;
    *(h8*)&t[r][c] = *(const h8*)(src + (size_t)r * NKV + c);
  }
  __syncthreads();
  _Float16* dst = vt + ((size_t)bg * NHD + dt * 64) * NS + st * 64;
#pragma unroll
  for (int it = 0; it < 2; ++it) {
    int idx = it * 256 + threadIdx.x;
    int r = idx >> 3, c = (idx & 7) * 8;
    h8 o;
#pragma unroll
    for (int e = 0; e < 8; ++e) o[e] = t[c + e][r];
    *(h8*)(dst + (size_t)r * NS + c) = o;
  }
}

// per (row, head): RMSNorm over 128, RoPE, *outScale, in-place f16 (K only now)
__global__ void norm_rope_kernel(_Float16* __restrict__ X, const float* __restrict__ scale,
                                 const float* __restrict__ cosT, const float* __restrict__ sinT,
                                 int hshift, int rowStride, float outScale) {
  int wid = threadIdx.x >> 6, lane = threadIdx.x & 63;
  int task = blockIdx.x * 4 + wid;
  int row = task >> hshift;
  int head = task & ((1 << hshift) - 1);
  _Float16* p = X + (size_t)row * rowStride + head * NHD;
  float x1 = (float)p[lane], x2 = (float)p[lane + 64];
  float ss = x1 * x1 + x2 * x2;
#pragma unroll
  for (int m = 1; m < 64; m <<= 1) ss += __shfl_xor(ss, m, 64);
  float rn = rsqrtf(ss * (1.0f / 128.0f) + 1e-6f);
  int s = row & (NS - 1);
  float c = cosT[s * 64 + lane], sn = sinT[s * 64 + lane];
  float n1 = x1 * rn * scale[lane], n2 = x2 * rn * scale[64 + lane];
  p[lane] = (_Float16)((n1 * c - n2 * sn) * outScale);
  p[lane + 64] = (_Float16)((n1 * sn + n2 * c) * outScale);
}

__device__ __forceinline__ void st_out(float* p, float v) { *p = v; }
__device__ __forceinline__ void st_out(_Float16* p, float v) { *p = (_Float16)v; }

// ---------------- GEMM 128x128 (2-phase) — used for the KV projection ----------------

template <typename OT>
__global__ __launch_bounds__(256, 3) void gemm_bt_kernel(
    const _Float16* __restrict__ A, const _Float16* __restrict__ Bt,
    const float* __restrict__ bias, OT* __restrict__ C, int N, int K) {
  __shared__ alignas(16) _Float16 As[128 * 64];
  __shared__ alignas(16) _Float16 Bs[128 * 64];
  const int tid = threadIdx.x;
  const int lane = tid & 63, wid = tid >> 6;
  const int wr = wid >> 1, wc = wid & 1;
  const int la = lane & 15, lb = (lane >> 4) * 8;
  const int bm = blockIdx.y * 128, bn = blockIdx.x * 128;

  fx4 acc[4][4] = {};

  for (int kt = 0; kt < K; kt += 64) {
    const _Float16* Ag = A + (size_t)bm * K + kt;
    const _Float16* Bg = Bt + (size_t)bn * K + kt;
#pragma unroll
    for (int it = 0; it < 4; ++it) {
      int cb = it * 256 + wid * 64;
      int ca = cb + lane;
      int r = ca >> 3, cc = ca & 7;
      gload16(Ag + (size_t)r * K + cc * 8, &As[cb * 8]);
      gload16(Bg + (size_t)r * K + cc * 8, &Bs[cb * 8]);
    }
    __syncthreads();
#pragma unroll
    for (int kk = 0; kk < 2; ++kk) {
      h8 af[4], bf[4];
#pragma unroll
      for (int m = 0; m < 4; ++m)
        af[m] = *(const h8*)&As[(wr * 64 + m * 16 + la) * 64 + kk * 32 + lb];
#pragma unroll
      for (int n = 0; n < 4; ++n)
        bf[n] = *(const h8*)&Bs[(wc * 64 + n * 16 + la) * 64 + kk * 32 + lb];
#pragma unroll
      for (int m = 0; m < 4; ++m)
#pragma unroll
        for (int n = 0; n < 4; ++n)
          acc[m][n] = __builtin_amdgcn_mfma_f32_16x16x32_f16(af[m], bf[n], acc[m][n], 0, 0, 0);
    }
    __syncthreads();
  }
#pragma unroll
  for (int m = 0; m < 4; ++m) {
    int row0 = bm + wr * 64 + m * 16 + (lane >> 4) * 4;
#pragma unroll
    for (int n = 0; n < 4; ++n) {
      int col = bn + wc * 64 + n * 16 + la;
      float bvv = bias[col];
#pragma unroll
      for (int r = 0; r < 4; ++r)
        st_out(&C[(size_t)(row0 + r) * N + col], acc[m][n][r] + bvv);
    }
  }
}

// ---------------- GEMM 256x256, fine-interleaved 4-phase (r8-verified) ------------
// 512 threads = 8 waves (2M x 4N). K-tile (BK=64) split into 2 k-halves of 32.
// LDS: As/Bs[2 buf][2 khalf][256*32] = 128 KB. Per phase: {ds_reads (4A, +4B at
// g=0) -> 2 stage gloads of tile kt+1 -> [ph1/ph3: vmcnt(4)] -> s_barrier ->
// lgkmcnt(0) -> setprio(1)+16 MFMA+setprio(0) -> s_barrier}. Seal chain in r8
// notes. Swizzle: chunk c ^= (r>>1)&3 (bank-verified free); inverse on stage
// source, forward on ds_read (rule 21). Measured: 75.5us, 0 conflicts.

template <typename OT>
__global__ __launch_bounds__(512, 2) void gemm256_kernel(
    const _Float16* __restrict__ A, const _Float16* __restrict__ Bt,
    const float* __restrict__ bias, OT* __restrict__ C, int N, int K) {
  __shared__ alignas(16) _Float16 As[2][2][256 * 32];
  __shared__ alignas(16) _Float16 Bs[2][2][256 * 32];
  const int tid = threadIdx.x;
  const int lane = tid & 63, w = tid >> 6;
  const int wr = w >> 2, wc = w & 3;
  const int la = lane & 15, lq = lane >> 4;
  const int lin = (blockIdx.x & 7) * 32 + (blockIdx.x >> 3);
  const int nbx = N >> 8;
  const int by = lin / nbx, bx = lin % nbx;
  const int bm = by * 256, bn = bx * 256;
  const int NT = K >> 6;

  fx4 acc[8][4] = {};

  {
    const _Float16* Ag = A + (size_t)bm * K;
    const _Float16* Bg = Bt + (size_t)bn * K;
#pragma unroll
    for (int sh = 0; sh < 2; ++sh) {
#pragma unroll
      for (int i = 0; i < 2; ++i) {
        int cb = i * 512 + w * 64;
        int s = cb + lane;
        int r = s >> 2, c = s & 3;
        gload16(Ag + (size_t)r * K + sh * 32 + ((c ^ ((r >> 1) & 3)) << 3), &As[0][sh][cb * 8]);
      }
#pragma unroll
      for (int i = 0; i < 2; ++i) {
        int cb = i * 512 + w * 64;
        int s = cb + lane;
        int r = s >> 2, c = s & 3;
        gload16(Bg + (size_t)r * K + sh * 32 + ((c ^ ((r >> 1) & 3)) << 3), &Bs[0][sh][cb * 8]);
      }
    }
  }
  asm volatile("s_waitcnt vmcnt(4)" ::: "memory");
  __builtin_amdgcn_s_barrier();

  for (int kt = 0; kt < NT; ++kt) {
    const int cur = kt & 1;
    const int nxt = cur ^ 1;
    const bool more = (kt + 1 < NT);
    const _Float16* Ag = A + (size_t)bm * K + (kt + 1) * 64;
    const _Float16* Bg = Bt + (size_t)bn * K + (kt + 1) * 64;
    h8 bf[4];
#pragma unroll
    for (int ph = 0; ph < 4; ++ph) {
      const int kh = ph >> 1, g = ph & 1;
      h8 af[4];
#pragma unroll
      for (int mi = 0; mi < 4; ++mi) {
        int row = wr * 128 + (g * 4 + mi) * 16 + la;
        af[mi] = *(const h8*)&As[cur][kh][row * 32 + ((lq ^ ((row >> 1) & 3)) << 3)];
      }
      if (g == 0) {
#pragma unroll
        for (int ni = 0; ni < 4; ++ni) {
          int row = wc * 64 + ni * 16 + la;
          bf[ni] = *(const h8*)&Bs[cur][kh][row * 32 + ((lq ^ ((row >> 1) & 3)) << 3)];
        }
      }
      if (more) {
        const int sh = ph >> 1;
        const _Float16* Sg = (ph & 1) ? Bg : Ag;
        _Float16* Ld = (ph & 1) ? &Bs[nxt][sh][0] : &As[nxt][sh][0];
#pragma unroll
        for (int i = 0; i < 2; ++i) {
          int cb = i * 512 + w * 64;
          int s = cb + lane;
          int r = s >> 2, c = s & 3;
          gload16(Sg + (size_t)r * K + sh * 32 + ((c ^ ((r >> 1) & 3)) << 3), Ld + cb * 8);
        }
      }
      if (ph == 1 || ph == 3) {
        if (more) asm volatile("s_waitcnt vmcnt(4)" ::: "memory");
        else      asm volatile("s_waitcnt vmcnt(0)" ::: "memory");
      }
      __builtin_amdgcn_s_barrier();
      asm volatile("s_waitcnt lgkmcnt(0)" ::: "memory");
      __builtin_amdgcn_sched_barrier(0);
      __builtin_amdgcn_s_setprio(1);
#pragma unroll
      for (int mi = 0; mi < 4; ++mi)
#pragma unroll
        for (int ni = 0; ni < 4; ++ni)
          acc[g * 4 + mi][ni] = __builtin_amdgcn_mfma_f32_16x16x32_f16(
              af[mi], bf[ni], acc[g * 4 + mi][ni], 0, 0, 0);
      __builtin_amdgcn_s_setprio(0);
      __builtin_amdgcn_sched_barrier(0);
      __builtin_amdgcn_s_barrier();
    }
  }
#pragma unroll
  for (int mi = 0; mi < 8; ++mi) {
    int row0 = bm + wr * 128 + mi * 16 + lq * 4;
#pragma unroll
    for (int ni = 0; ni < 4; ++ni) {
      int col = bn + wc * 64 + ni * 16 + la;
      float bvv = bias[col];
#pragma unroll
      for (int r = 0; r < 4; ++r)
        st_out(&C[(size_t)(row0 + r) * N + col], acc[mi][ni][r] + bvv);
    }
  }
}

// ---------------- flash attention (r8-proven schedule + fused Q norm/rope) --------
// 512 blocks x 512 threads; block = (q-tile pair {j,15-j}, g, b); 9 kt-tiles.
// Tile loop: __syncthreads (full drain: prev stage landed + all reads of the
// buffer about to be overwritten done) -> stage(next) -> compute. Stage has the
// whole tile's compute to hide under (full-tile prefetch depth).
// Q path fused: raw Q-projection rows are loaded once per q-tile and
// RMSNorm+RoPE+HEAD_SCALE applied in-register (bit-identical math to the old
// norm kernel: f32 ops, f16 cast at the same point).

__global__ __launch_bounds__(512, 4) void attn_kernel(
    const _Float16* __restrict__ Q, const _Float16* __restrict__ KV,
    const _Float16* __restrict__ Vt, _Float16* __restrict__ ctx,
    const float* __restrict__ qns, const float* __restrict__ cosT,
    const float* __restrict__ sinT) {
  __shared__ alignas(16) _Float16 Ks[2][64 * 128];
  __shared__ alignas(16) _Float16 Vs[2][128 * 64];
  __shared__ alignas(16) _Float16 Ps[8][16 * 64];

  const int bid = blockIdx.x;
  const int logical = (bid & 7) * 64 + (bid >> 3);
  const int b = logical >> 5;
  const int g = (logical >> 3) & 3;
  const int jp = logical & 7;
  const int j1 = jp, j2 = 15 - jp;

  const int tid = threadIdx.x;
  const int lane = tid & 63, w = tid >> 6;
  const int la = lane & 15, lq = lane >> 4;
  const int h = g * 4 + (w & 3);
  const int rh = w >> 2;

  const _Float16* Vg = Vt + (size_t)(b * NG + g) * NHD * NS;

  auto stage = [&](int buf, int kt) {
    const _Float16* Kg = KV + ((size_t)(b * NS + kt * 64)) * NKV + g * NHD;
#pragma unroll
    for (int it = 0; it < 2; ++it) {
      int cb = it * 512 + w * 64;
      int s = cb + lane;
      int rr = s >> 4, c = s & 15;
      gload16(Kg + (size_t)rr * NKV + ((c ^ (rr & 7)) * 8), &Ks[buf][cb * 8]);
    }
#pragma unroll
    for (int it = 0; it < 2; ++it) {
      int cb = it * 512 + w * 64;
      int s = cb + lane;
      int rr = s >> 3, c = s & 7;
      gload16(Vg + (size_t)rr * NS + kt * 64 + ((c ^ (rr & 7)) * 8), &Vs[buf][cb * 8]);
    }
  };

  const int nt1 = ((j1 * 32 + 31) >> 6) + 1;
  const int nt2 = ((j2 * 32 + 31) >> 6) + 1;
  const int ntotal = nt1 + nt2;  // == 9

  h8 qf[4];
  fx4 oacc[8];
  float mrun[4], lrun[4];

  stage(0, 0);
  int cur = 0;
  for (int t = 0; t < ntotal; ++t) {
    const bool inA = t < nt1;
    const int j = inA ? j1 : j2;
    const int kt = inA ? t : t - nt1;
    const int ntj = inA ? nt1 : nt2;
    __syncthreads();  // drains vmcnt(0): buf[cur] staged; all waves done with buf[cur^1]
    if (t + 1 < ntotal) {
      int nkt = (t + 1 < nt1) ? (t + 1) : (t + 1 - nt1);
      stage(cur ^ 1, nkt);
    }
    if (kt == 0) {  // new q-tile: load raw Q row, fused RMSNorm+RoPE+HEAD_SCALE
      const int qrow = j * 32 + rh * 16 + la;
      const _Float16* Qg = Q + ((size_t)(b * NS + qrow)) * ND + h * NHD + lq * 8;
      float xq[4][8];
      float ss = 0.f;
#pragma unroll
      for (int kc = 0; kc < 4; ++kc) {
        h8 v = *(const h8*)(Qg + kc * 32);
#pragma unroll
        for (int e = 0; e < 8; ++e) { xq[kc][e] = (float)v[e]; ss += xq[kc][e] * xq[kc][e]; }
      }
      ss += __shfl_xor(ss, 16, 64);  // combine the 4 lanes (lq=0..3) holding this row
      ss += __shfl_xor(ss, 32, 64);
      float rn = rsqrtf(ss * (1.0f / 128.0f) + 1e-6f);
#pragma unroll
      for (int kc = 0; kc < 2; ++kc) {
        const float* s1p = qns + kc * 32 + lq * 8;
        const float* s2p = qns + (kc + 2) * 32 + lq * 8;
        const float* ctp = cosT + qrow * 64 + kc * 32 + lq * 8;
        const float* stp = sinT + qrow * 64 + kc * 32 + lq * 8;
        fx4 s1a = *(const fx4*)s1p, s1b = *(const fx4*)(s1p + 4);
        fx4 s2a = *(const fx4*)s2p, s2b = *(const fx4*)(s2p + 4);
        fx4 ca = *(const fx4*)ctp, cb2 = *(const fx4*)(ctp + 4);
        fx4 sa = *(const fx4*)stp, sb = *(const fx4*)(stp + 4);
#pragma unroll
        for (int e = 0; e < 8; ++e) {
          float sc1 = (e < 4) ? s1a[e & 3] : s1b[e & 3];
          float sc2 = (e < 4) ? s2a[e & 3] : s2b[e & 3];
          float cc = (e < 4) ? ca[e & 3] : cb2[e & 3];
          float sn = (e < 4) ? sa[e & 3] : sb[e & 3];
          float n1 = xq[kc][e] * rn * sc1;
          float n2 = xq[kc + 2][e] * rn * sc2;
          qf[kc][e] = (_Float16)((n1 * cc - n2 * sn) * HEAD_SCALE);
          qf[kc + 2][e] = (_Float16)((n1 * sn + n2 * cc) * HEAD_SCALE);
        }
      }
#pragma unroll
      for (int f = 0; f < 8; ++f) oacc[f] = fx4{0.f, 0.f, 0.f, 0.f};
#pragma unroll
      for (int r = 0; r < 4; ++r) { mrun[r] = -1e30f; lrun[r] = 0.f; }
    }

    // QK^T: 16 q-rows x 64 kv
    fx4 sc[4] = {};
    __builtin_amdgcn_s_setprio(1);
#pragma unroll
    for (int n = 0; n < 4; ++n) {
      int row = n * 16 + la;
#pragma unroll
      for (int kc = 0; kc < 4; ++kc) {
        h8 bk = *(const h8*)&Ks[cur][row * 128 + (((kc * 4 + lq) ^ (la & 7)) * 8)];
        sc[n] = __builtin_amdgcn_mfma_f32_16x16x32_f16(qf[kc], bk, sc[n], 0, 0, 0);
      }
    }
    __builtin_amdgcn_s_setprio(0);

    const int qrow0 = j * 32 + rh * 16 + lq * 4;
    const bool maskT = (kt == ntj - 1);
    float pv[4][4];
    float rm[4] = {-1e30f, -1e30f, -1e30f, -1e30f};
#pragma unroll
    for (int n = 0; n < 4; ++n) {
      int kv = kt * 64 + n * 16 + la;
#pragma unroll
      for (int r = 0; r < 4; ++r) {
        float sv = sc[n][r] * HEAD_SCALE;
        sv = (maskT && kv > qrow0 + r) ? -1e30f : sv;
        pv[n][r] = sv;
        rm[r] = fmaxf(rm[r], sv);
      }
    }
#pragma unroll
    for (int r = 0; r < 4; ++r) {
#pragma unroll
      for (int m = 1; m < 16; m <<= 1) rm[r] = fmaxf(rm[r], __shfl_xor(rm[r], m, 64));
      float mn = fmaxf(mrun[r], rm[r]);
      float corr = __expf(mrun[r] - mn);
      mrun[r] = mn;
      lrun[r] *= corr;
#pragma unroll
      for (int f = 0; f < 8; ++f) oacc[f][r] *= corr;
    }
    float rs[4] = {0.f, 0.f, 0.f, 0.f};
#pragma unroll
    for (int n = 0; n < 4; ++n)
#pragma unroll
      for (int r = 0; r < 4; ++r) {
        float e = __expf(pv[n][r] - mrun[r]);
        pv[n][r] = e;
        rs[r] += e;
      }
#pragma unroll
    for (int r = 0; r < 4; ++r) {
#pragma unroll
      for (int m = 1; m < 16; m <<= 1) rs[r] += __shfl_xor(rs[r], m, 64);
      lrun[r] += rs[r];
    }

    // P (C-layout) -> LDS (swizzled) -> reload in A-layout (wave-local)
#pragma unroll
    for (int n = 0; n < 4; ++n)
#pragma unroll
      for (int r = 0; r < 4; ++r) {
        int row = lq * 4 + r;
        int chsw = (n * 2 + (la >> 3)) ^ (row & 7);
        Ps[w][row * 64 + chsw * 8 + (la & 7)] = (_Float16)pv[n][r];
      }
    asm volatile("s_waitcnt lgkmcnt(0)" ::: "memory");
    __builtin_amdgcn_sched_barrier(0);
    h8 pf[2];
#pragma unroll
    for (int ks = 0; ks < 2; ++ks)
      pf[ks] = *(const h8*)&Ps[w][la * 64 + (((ks * 4 + lq) ^ (la & 7)) * 8)];

    // PV
    __builtin_amdgcn_s_setprio(1);
#pragma unroll
    for (int f = 0; f < 8; ++f) {
      int row = f * 16 + la;
#pragma unroll
      for (int ks = 0; ks < 2; ++ks) {
        h8 bv = *(const h8*)&Vs[cur][row * 64 + (((ks * 4 + lq) ^ (la & 7)) * 8)];
        oacc[f] = __builtin_amdgcn_mfma_f32_16x16x32_f16(pf[ks], bv, oacc[f], 0, 0, 0);
      }
    }
    __builtin_amdgcn_s_setprio(0);

    if (maskT) {
      _Float16* Cg = ctx + ((size_t)(b * NS + qrow0)) * ND + h * NHD + la;
      float inv_l[4];
#pragma unroll
      for (int r = 0; r < 4; ++r) inv_l[r] = 1.0f / lrun[r];
#pragma unroll
      for (int f = 0; f < 8; ++f)
#pragma unroll
        for (int r = 0; r < 4; ++r)
          Cg[(size_t)r * ND + f * 16] = (_Float16)(oacc[f][r] * inv_l[r]);
    }
    cur ^= 1;
  }
}

// ---------------- launch ----------------

extern "C" void kernel_launch(void* const* d_in, const int* in_sizes, int n_in,
                              void* d_out, int out_size, void* d_ws, size_t ws_size,
                              hipStream_t stream) {
  (void)in_sizes; (void)n_in; (void)out_size; (void)ws_size;
  const float* x = (const float*)d_in[0];
  const float* wq = (const float*)d_in[1];
  const float* bq = (const float*)d_in[2];
  const float* wk = (const float*)d_in[3];
  const float* bk = (const float*)d_in[4];
  const float* wv = (const float*)d_in[5];
  const float* bv = (const float*)d_in[6];
  const float* wo = (const float*)d_in[7];
  const float* bo = (const float*)d_in[8];
  const float* qns = (const float*)d_in[9];
  const float* kns = (const float*)d_in[10];

  char* ws = (char*)d_ws;
  size_t off = 0;
  _Float16* xh = (_Float16*)(ws + off); off += (size_t)NM * ND * 2;       // 32MB
  _Float16* wqt = (_Float16*)(ws + off); off += (size_t)ND * ND * 2;      // 8MB
  _Float16* wkvt = (_Float16*)(ws + off); off += (size_t)NKV * ND * 2;    // 4MB
  _Float16* wot = (_Float16*)(ws + off); off += (size_t)ND * ND * 2;      // 8MB
  _Float16* Qb = (_Float16*)(ws + off); off += (size_t)NM * ND * 2;       // 32MB
  _Float16* KVbuf = (_Float16*)(ws + off); off += (size_t)NM * NKV * 2;   // 16MB
  float* cosT = (float*)(ws + off); off += (size_t)NS * 64 * 4;
  float* sinT = (float*)(ws + off); off += (size_t)NS * 64 * 4;
  float* bkv = (float*)(ws + off); off += (size_t)NKV * 4;
  _Float16* ctx = xh;            // xh dead after KV GEMM; reuse
  _Float16* Vtg = wqt;           // wqt dead after Q GEMM; reuse

  prep_kernel<<<dim3(4737), 256, 0, stream>>>(x, xh, wq, wqt, wk, wv, wkvt, wo, wot,
                                              cosT, sinT, bk, bv, bkv);

  gemm256_kernel<_Float16><<<dim3(256), dim3(512), 0, stream>>>(xh, wqt, bq, Qb, ND, ND);
  gemm_bt_kernel<_Float16><<<dim3(NKV / 128, NM / 128), 256, 0, stream>>>(xh, wkvt, bkv, KVbuf, NKV, ND);

  norm_rope_kernel<<<dim3(NM * NG / 4), 256, 0, stream>>>(KVbuf, kns, cosT, sinT, 2, NKV, 1.0f);

  vtrans_kernel<<<dim3(NS / 64, NHD / 64, NB * NG), 256, 0, stream>>>(KVbuf, Vtg);

  attn_kernel<<<dim3(512), dim3(512), 0, stream>>>(Qb, KVbuf, Vtg, ctx, qns, cosT, sinT);

  gemm256_kernel<float><<<dim3(256), dim3(512), 0, stream>>>(ctx, wot, bo, (float*)d_out, ND, ND);
}